// Round 3
// baseline (258.652 us; speedup 1.0000x reference)
//
#include <hip/hip_runtime.h>
#include <stdint.h>

#define DEV static __device__ __forceinline__

typedef __attribute__((ext_vector_type(4)))  float f32x4;
typedef __attribute__((ext_vector_type(16))) float f32x16;
typedef __bf16 bf16x8 __attribute__((ext_vector_type(8)));

// ---------------- problem constants ----------------
constexpr int Bc = 2, S = 2048, Dm = 1024, H = 16, DH = 64;
constexpr int BS  = Bc * S;                 // 4096 rows
constexpr int HSZ = Bc * H * S * DH;        // 4,194,304 elems per head tensor

// ws layout (byte offsets)
constexpr size_t OFF_QKVB  = 0;              // [3][4096][1024] bf16   25,165,824
constexpr size_t OFF_WT    = 25165824;       // [4][1024][1024] bf16    8,388,608
constexpr size_t OFF_HEADS = 33554432;       // [3][2][16][2048][64]   25,165,824
constexpr size_t OFF_VT    = 58720256;       // [2][16][64][2048]       8,388,608
constexpr size_t OFF_O     = 67108864;       // [4096][1024] bf16       8,388,608

// ---------------- helpers ----------------
DEV uint16_t f2bf(float f) {                  // fp32 -> bf16 RNE (cold paths)
    uint32_t u = __float_as_uint(f);
    uint32_t r = u + 0x7FFFu + ((u >> 16) & 1u);
    return (uint16_t)(r >> 16);
}
DEV uint32_t cvtpk(float lo, float hi) {      // 1-instr packed fp32->bf16x2
    uint32_t r;
    asm("v_cvt_pk_bf16_f32 %0, %1, %2" : "=v"(r) : "v"(lo), "v"(hi));
    return r;
}
DEV float clip15(float x, float c15) {        // clamp(x,0,15) = med3(x,0,15)
    float r;
    asm("v_med3_f32 %0, %1, 0, %2" : "=v"(r) : "v"(x), "v"(c15));
    return r;
}
// XOR swizzle for LDS tiles with 128-byte rows: 16B-chunk ^= (row & 7).
DEV uint32_t swz128(uint32_t byteoff) {
    return byteoff ^ (((byteoff >> 7) & 7u) << 4);
}
DEV void gll16(const void* g, void* l) {      // async global -> LDS, 16B per lane
    auto gp = (const __attribute__((address_space(1))) uint32_t*)g;
    auto lp = (__attribute__((address_space(3))) uint32_t*)l;
    __builtin_amdgcn_global_load_lds(gp, lp, 16, 0, 0);
}
DEV bf16x8 ld_frag(const char* base, uint32_t logical_off) {  // swizzled LDS read
    return __builtin_bit_cast(bf16x8, *(const uint4*)(base + swz128(logical_off)));
}
DEV bf16x8 ld_frag_g(const void* p) {         // 16B global read
    return __builtin_bit_cast(bf16x8, *(const uint4*)p);
}

// ---------------- kernel 1: convert q,k,v fp32 -> bf16 [3][4096][1024] ----------------
__global__ __launch_bounds__(256) void k_convert(const float* __restrict__ q,
                                                 const float* __restrict__ k,
                                                 const float* __restrict__ v,
                                                 uint16_t* __restrict__ out) {
    const int64_t n1 = (int64_t)BS * Dm;
    int64_t i = ((int64_t)blockIdx.x * 256 + threadIdx.x) * 8;
    const float* src; int64_t j;
    if (i < n1)            { src = q; j = i; }
    else if (i < 2 * n1)   { src = k; j = i - n1; }
    else                   { src = v; j = i - 2 * n1; }
    float4 a = *(const float4*)(src + j);
    float4 b = *(const float4*)(src + j + 4);
    union { uint16_t u[8]; uint4 q4; } o;
    o.u[0] = f2bf(a.x); o.u[1] = f2bf(a.y); o.u[2] = f2bf(a.z); o.u[3] = f2bf(a.w);
    o.u[4] = f2bf(b.x); o.u[5] = f2bf(b.y); o.u[6] = f2bf(b.z); o.u[7] = f2bf(b.w);
    *(uint4*)(out + i) = o.q4;
}

// ---------------- kernel 2: W^T bf16 (scale folded into Wq) ----------------
__global__ __launch_bounds__(256) void k_transw(const float* __restrict__ w0,
                                                const float* __restrict__ w1,
                                                const float* __restrict__ w2,
                                                const float* __restrict__ w3,
                                                uint16_t* __restrict__ wt) {
    int mat = blockIdx.y;
    const float* w = (mat == 0) ? w0 : (mat == 1) ? w1 : (mat == 2) ? w2 : w3;
    float scale = (mat == 0) ? 0.125f : 1.0f;     // 1/sqrt(64) folded into Wq
    uint16_t* out = wt + (size_t)mat * 1024 * 1024;
    int tile = blockIdx.x;                        // 16x16 tiles of 64x64
    int tr = (tile >> 4) << 6, tc = (tile & 15) << 6;   // tr = k0, tc = n0
    __shared__ float lds[64][65];
    int t = threadIdx.x;
#pragma unroll
    for (int p = 0; p < 4; ++p) {
        int r = p * 16 + (t >> 4);
        int c = (t & 15) * 4;
        float4 x = *(const float4*)(w + (size_t)(tr + r) * 1024 + tc + c);
        lds[r][c] = x.x; lds[r][c + 1] = x.y; lds[r][c + 2] = x.z; lds[r][c + 3] = x.w;
    }
    __syncthreads();
    int n = t >> 2, kc = (t & 3) * 16;
    union { uint16_t u[16]; uint4 q[2]; } tt;
#pragma unroll
    for (int j = 0; j < 16; ++j) tt.u[j] = f2bf(lds[kc + j][n] * scale);
    uint16_t* dst = out + (size_t)(tc + n) * 1024 + tr + kc;   // WT[n][k]
    *(uint4*)dst = tt.q[0];
    *(uint4*)(dst + 8) = tt.q[1];
}

// ---------------- shared GEMM core: 128x128 tile, BK=64, 4 waves ----------------
// Ta = MFMA A-operand tile (rows index C's reg/row dim), Tb = B-operand tile
// (rows index C's col dim). Both [128][K] bf16 row-major, pre-offset.
struct Acc { f32x4 a[4][4]; };

DEV void stage128(const uint16_t* g, int ldbytes, char* lds) {
    int tid = threadIdx.x;                        // 256 thr x 4 issues x 16B = 16KB
#pragma unroll
    for (int it = 0; it < 4; ++it) {
        uint32_t p = it * 4096 + tid * 16;        // physical LDS offset this lane fills
        uint32_t lo = swz128(p);                  // -> logical: pre-swizzled source
        uint32_t row = lo >> 7, col = lo & 127;
        gll16((const char*)g + (size_t)row * ldbytes + col,
              lds + it * 4096 + (tid & ~63) * 16);  // wave-uniform base + lane*16
    }
}

DEV void gemm_core(const uint16_t* Ta, const uint16_t* Tb, int K,
                   char* la, char* lb, Acc& acc) {
    int lane = threadIdx.x & 63, w = threadIdx.x >> 6;
    int wr = w >> 1, wc = w & 1;
#pragma unroll
    for (int ia = 0; ia < 4; ++ia)
#pragma unroll
        for (int ib = 0; ib < 4; ++ib)
#pragma unroll
            for (int r = 0; r < 4; ++r) acc.a[ia][ib][r] = 0.f;
    for (int k0 = 0; k0 < K; k0 += 64) {
        __syncthreads();                          // prev reads done -> LDS reusable
        stage128(Ta + k0, K * 2, la);
        stage128(Tb + k0, K * 2, lb);
        __syncthreads();                          // staged data visible
#pragma unroll
        for (int kk = 0; kk < 2; ++kk) {
            bf16x8 af[4], bfr[4];
#pragma unroll
            for (int ia = 0; ia < 4; ++ia) {
                uint32_t row = wr * 64 + ia * 16 + (lane & 15);
                af[ia] = ld_frag(la, row * 128 + kk * 64 + (lane >> 4) * 16);
            }
#pragma unroll
            for (int ib = 0; ib < 4; ++ib) {
                uint32_t row = wc * 64 + ib * 16 + (lane & 15);
                bfr[ib] = ld_frag(lb, row * 128 + kk * 64 + (lane >> 4) * 16);
            }
#pragma unroll
            for (int ia = 0; ia < 4; ++ia)
#pragma unroll
                for (int ib = 0; ib < 4; ++ib)
                    acc.a[ia][ib] = __builtin_amdgcn_mfma_f32_16x16x32_bf16(
                        af[ia], bfr[ib], acc.a[ia][ib], 0, 0, 0);
        }
    }
}

// ---------------- kernel 3: fused QKV projection GEMM ----------------
// A-operand = W^T tile  =>  C[n][m]: lane holds 4 CONSECUTIVE n per r-group
// -> 8B vector stores into the head-split layout.
__global__ __launch_bounds__(256) void k_proj(const uint16_t* __restrict__ qkvb,
                                              const uint16_t* __restrict__ WT,
                                              uint16_t* __restrict__ heads) {
    __shared__ char lds[32768];
    int raw = blockIdx.x;                     // 768 blocks; XCD-chunked swizzle
    int blk = (raw & 7) * 96 + (raw >> 3);
    int sel = blk >> 8;
    int t2 = blk & 255; int bm = t2 >> 3, bn = t2 & 7;
    const uint16_t* Act = qkvb + (size_t)sel * BS * Dm + (size_t)bm * 128 * Dm;
    const uint16_t* Wtt = WT   + (size_t)sel * Dm * Dm + (size_t)bn * 128 * Dm;
    Acc acc;
    gemm_core(Wtt, Act, 1024, lds, lds + 16384, acc);   // A=weights, B=acts
    uint16_t* out = heads + (size_t)sel * HSZ;
    int lane = threadIdx.x & 63, w = threadIdx.x >> 6;
    int na = bn * 128 + (w >> 1) * 64, mb = bm * 128 + (w & 1) * 64;
#pragma unroll
    for (int ia = 0; ia < 4; ++ia)
#pragma unroll
        for (int ib = 0; ib < 4; ++ib) {
            int n0 = na + ia * 16 + (lane >> 4) * 4;     // 4 consecutive cols
            int m  = mb + ib * 16 + (lane & 15);
            uint2 d;
            d.x = cvtpk(acc.a[ia][ib][0], acc.a[ia][ib][1]);
            d.y = cvtpk(acc.a[ia][ib][2], acc.a[ia][ib][3]);
            int b = m >> 11, s = m & 2047, h = n0 >> 6, dd = n0 & 63;
            *(uint2*)(out + (((size_t)(b * H + h)) * S + s) * 64 + dd) = d;
        }
}

// ---------------- kernel 4: Vh [bh][s][64] -> Vt [bh][64][s] ----------------
__global__ __launch_bounds__(256) void k_transv(const uint16_t* __restrict__ Vh,
                                                uint16_t* __restrict__ Vt) {
    int bh = blockIdx.x >> 5, st = blockIdx.x & 31;
    int s0 = st * 64;
    const uint16_t* src = Vh + (size_t)bh * S * 64 + (size_t)s0 * 64;
    uint16_t* dst = Vt + (size_t)bh * 64 * S;
    __shared__ uint16_t lds[64][65];
    int t = threadIdx.x;
    {
        int r = t >> 2, c = (t & 3) * 16;
        union { uint16_t u[16]; uint4 q[2]; } x;
        x.q[0] = *(const uint4*)(src + (size_t)r * 64 + c);
        x.q[1] = *(const uint4*)(src + (size_t)r * 64 + c + 8);
#pragma unroll
        for (int j = 0; j < 16; ++j) lds[r][c + j] = x.u[j];
    }
    __syncthreads();
    {
        int d = t >> 2, sc = (t & 3) * 16;
        union { uint16_t u[16]; uint4 q[2]; } x;
#pragma unroll
        for (int j = 0; j < 16; ++j) x.u[j] = lds[sc + j][d];
        uint16_t* p = dst + (size_t)d * S + s0 + sc;
        *(uint4*)p = x.q[0];
        *(uint4*)(p + 8) = x.q[1];
    }
}

// ---------------- kernel 5: fused ReLU15 attention ----------------
// 512 blocks = 32 heads x 16 q-blocks of 128 rows; 128 threads = 2 waves.
// Each wave owns 64 q-rows as 2 subtiles of 32 that SHARE the K/V LDS
// fragments -> halves LDS-read bytes per MFMA (the R2 bottleneck).
// S^T = mfma(A=K,B=Q) -> lane owns P[kv][q=l31]; cvt_pk + permlane32_swap
// repacks to PV operand in-register. PV computed as mfma(A=V^T,B=P) so the
// O epilogue gets 4 consecutive dv per r-group -> 8B stores.
__global__ __launch_bounds__(128) void k_attn(const uint16_t* __restrict__ Qh,
                                              const uint16_t* __restrict__ Kh,
                                              const uint16_t* __restrict__ Vt,
                                              uint16_t* __restrict__ O) {
    __shared__ char kbuf[2][8192];
    __shared__ char vbuf[2][8192];
    int raw = blockIdx.x;
    int bid = (raw & 7) * 64 + (raw >> 3);    // XCD-chunked: 4 heads per XCD chunk
    int bh = bid >> 4, qb = (bid & 15) * 128;
    int tid = threadIdx.x, lane = tid & 63, w = tid >> 6;
    int l31 = lane & 31, hi = lane >> 5;
    const char* Kbase = (const char*)(Kh + (size_t)bh * S * 64);
    const char* Vbase = (const char*)(Vt + (size_t)bh * 64 * S);

    bf16x8 qf[2][4];
#pragma unroll
    for (int qs = 0; qs < 2; ++qs) {
        const char* qrow = (const char*)(Qh + (size_t)bh * S * 64
                                         + (size_t)(qb + w * 64 + qs * 32 + l31) * 64);
#pragma unroll
        for (int ks = 0; ks < 4; ++ks)
            qf[qs][ks] = ld_frag_g(qrow + ks * 32 + hi * 16);
    }
    f32x16 oa[2][2];
#pragma unroll
    for (int qs = 0; qs < 2; ++qs)
#pragma unroll
        for (int nt = 0; nt < 2; ++nt)
#pragma unroll
            for (int r = 0; r < 16; ++r) oa[qs][nt][r] = 0.f;
    float c15 = 15.0f;

    auto stageKV = [&](int tile, int bufi) {    // 128 thr x 4 issues x 16B x2 tiles
        int kv0 = tile * 64;
#pragma unroll
        for (int it = 0; it < 4; ++it) {
            uint32_t p = it * 2048 + tid * 16;
            uint32_t lo = swz128(p);
            uint32_t row = lo >> 7, col = lo & 127;
            gll16(Kbase + (size_t)(kv0 + row) * 128 + col,
                  kbuf[bufi] + it * 2048 + (tid & ~63) * 16);
            gll16(Vbase + (size_t)row * 4096 + (size_t)kv0 * 2 + col,
                  vbuf[bufi] + it * 2048 + (tid & ~63) * 16);
        }
    };

    stageKV(0, 0);
    __syncthreads();
    for (int t = 0; t < 32; ++t) {
        int cur = t & 1;
        if (t < 31) stageKV(t + 1, cur ^ 1);   // in flight across compute
        __builtin_amdgcn_s_setprio(1);
#pragma unroll
        for (int mt = 0; mt < 2; ++mt) {
            bf16x8 kf[4];
#pragma unroll
            for (int ks = 0; ks < 4; ++ks)
                kf[ks] = ld_frag(kbuf[cur], (mt * 32 + l31) * 128 + ks * 32 + hi * 16);
            bf16x8 pa[2][2];
#pragma unroll
            for (int qs = 0; qs < 2; ++qs) {
                f32x16 c;
#pragma unroll
                for (int r = 0; r < 16; ++r) c[r] = 0.f;
#pragma unroll
                for (int ks = 0; ks < 4; ++ks)
                    c = __builtin_amdgcn_mfma_f32_32x32x16_bf16(kf[ks], qf[qs][ks], c, 0, 0, 0);
#pragma unroll
                for (int r = 0; r < 16; ++r) c[r] = clip15(c[r], c15);
                // lane holds kv=(r&3)+8*(r>>2)+4*hi; operand needs kv=ks2*16+hi*8+j
#pragma unroll
                for (int ks2 = 0; ks2 < 2; ++ks2) {
                    union { uint32_t w[4]; bf16x8 v; } up;
#pragma unroll
                    for (int jj = 0; jj < 2; ++jj) {
                        uint32_t sA = cvtpk(c[8 * ks2 + 2 * jj],     c[8 * ks2 + 2 * jj + 1]);
                        uint32_t sB = cvtpk(c[8 * ks2 + 4 + 2 * jj], c[8 * ks2 + 4 + 2 * jj + 1]);
                        asm volatile("v_permlane32_swap_b32 %0, %1" : "+v"(sA), "+v"(sB));
                        up.w[jj] = sA; up.w[2 + jj] = sB;
                    }
                    pa[qs][ks2] = up.v;
                }
            }
#pragma unroll
            for (int ks2 = 0; ks2 < 2; ++ks2)
#pragma unroll
                for (int nt = 0; nt < 2; ++nt) {
                    bf16x8 vb = ld_frag(vbuf[cur],
                                        (nt * 32 + l31) * 128 + mt * 64 + ks2 * 32 + hi * 16);
#pragma unroll
                    for (int qs = 0; qs < 2; ++qs)
                        oa[qs][nt] = __builtin_amdgcn_mfma_f32_32x32x16_bf16(
                            vb, pa[qs][ks2], oa[qs][nt], 0, 0, 0);
                }
        }
        __builtin_amdgcn_s_setprio(0);
        __syncthreads();   // waves done reading cur; next stage drained & visible
    }
    int b = bh >> 4, h = bh & 15;
#pragma unroll
    for (int qs = 0; qs < 2; ++qs) {
        int q = qb + w * 64 + qs * 32 + l31;                  // C col = q
#pragma unroll
        for (int nt = 0; nt < 2; ++nt)
#pragma unroll
            for (int g = 0; g < 4; ++g) {                      // dv = 8g+4hi+0..3
                uint2 d;
                d.x = cvtpk(oa[qs][nt][4 * g],     oa[qs][nt][4 * g + 1]);
                d.y = cvtpk(oa[qs][nt][4 * g + 2], oa[qs][nt][4 * g + 3]);
                int col = h * 64 + nt * 32 + 8 * g + 4 * hi;
                *(uint2*)(O + ((size_t)(b * S + q)) * 1024 + col) = d;
            }
    }
}

// ---------------- kernel 6: FC GEMM + residual -> d_out fp32 ----------------
__global__ __launch_bounds__(256) void k_fc(const uint16_t* __restrict__ Ob,
                                            const uint16_t* __restrict__ WfcT,
                                            const float* __restrict__ resid,
                                            float* __restrict__ out) {
    __shared__ char lds[32768];
    int raw = blockIdx.x;                     // 256 blocks; XCD swizzle
    int blk = (raw & 7) * 32 + (raw >> 3);
    int bm = blk >> 3, bn = blk & 7;
    const uint16_t* Act = Ob   + (size_t)bm * 128 * Dm;
    const uint16_t* Wtt = WfcT + (size_t)bn * 128 * Dm;
    Acc acc;
    gemm_core(Wtt, Act, 1024, lds, lds + 16384, acc);   // A=weights -> C[n][m]
    int lane = threadIdx.x & 63, w = threadIdx.x >> 6;
    int na = bn * 128 + (w >> 1) * 64, mb = bm * 128 + (w & 1) * 64;
#pragma unroll
    for (int ia = 0; ia < 4; ++ia)
#pragma unroll
        for (int ib = 0; ib < 4; ++ib) {
            int n0 = na + ia * 16 + (lane >> 4) * 4;
            int m  = mb + ib * 16 + (lane & 15);
            size_t idx = (size_t)m * 1024 + n0;
            float4 r4 = *(const float4*)(resid + idx);
            float4 o;
            o.x = acc.a[ia][ib][0] + r4.x;
            o.y = acc.a[ia][ib][1] + r4.y;
            o.z = acc.a[ia][ib][2] + r4.z;
            o.w = acc.a[ia][ib][3] + r4.w;
            *(float4*)(out + idx) = o;
        }
}

// ---------------- kernel 7: LayerNorm in-place on d_out ----------------
__global__ __launch_bounds__(256) void k_ln(float* __restrict__ io,
                                            const float* __restrict__ gamma,
                                            const float* __restrict__ beta) {
    int row = blockIdx.x;
    float* p = io + (size_t)row * 1024;
    int t = threadIdx.x;
    float4 x = *(const float4*)(p + t * 4);
    float s  = x.x + x.y + x.z + x.w;
    float s2 = x.x * x.x + x.y * x.y + x.z * x.z + x.w * x.w;
#pragma unroll
    for (int o = 32; o > 0; o >>= 1) { s += __shfl_xor(s, o); s2 += __shfl_xor(s2, o); }
    __shared__ float red[8];
    int w = t >> 6, lane = t & 63;
    if (lane == 0) { red[w] = s; red[4 + w] = s2; }
    __syncthreads();
    s  = red[0] + red[1] + red[2] + red[3];
    s2 = red[4] + red[5] + red[6] + red[7];
    float mu  = s * (1.f / 1024.f);
    float var = s2 * (1.f / 1024.f) - mu * mu;
    float inv = rsqrtf(var + 1e-6f);
    float4 g  = *(const float4*)(gamma + t * 4);
    float4 bb = *(const float4*)(beta + t * 4);
    x.x = (x.x - mu) * inv * g.x + bb.x;
    x.y = (x.y - mu) * inv * g.y + bb.y;
    x.z = (x.z - mu) * inv * g.z + bb.z;
    x.w = (x.w - mu) * inv * g.w + bb.w;
    *(float4*)(p + t * 4) = x;
}

// ---------------- launcher ----------------
extern "C" void kernel_launch(void* const* d_in, const int* in_sizes, int n_in,
                              void* d_out, int out_size, void* d_ws, size_t ws_size,
                              hipStream_t stream) {
    (void)in_sizes; (void)n_in; (void)out_size; (void)ws_size;
    const float* q     = (const float*)d_in[0];
    const float* k     = (const float*)d_in[1];
    const float* v     = (const float*)d_in[2];
    const float* Wq    = (const float*)d_in[3];
    const float* Wk    = (const float*)d_in[4];
    const float* Wv    = (const float*)d_in[5];
    const float* Wfc   = (const float*)d_in[6];
    const float* gamma = (const float*)d_in[7];
    const float* beta  = (const float*)d_in[8];
    char* ws = (char*)d_ws;
    uint16_t* qkvb  = (uint16_t*)(ws + OFF_QKVB);
    uint16_t* WT    = (uint16_t*)(ws + OFF_WT);
    uint16_t* heads = (uint16_t*)(ws + OFF_HEADS);
    uint16_t* Vt    = (uint16_t*)(ws + OFF_VT);
    uint16_t* Ob    = (uint16_t*)(ws + OFF_O);
    float* out = (float*)d_out;

    k_convert<<<dim3(6144), dim3(256), 0, stream>>>(q, k, v, qkvb);
    k_transw <<<dim3(256, 4), dim3(256), 0, stream>>>(Wq, Wk, Wv, Wfc, WT);
    k_proj   <<<dim3(768), dim3(256), 0, stream>>>(qkvb, WT, heads);
    k_transv <<<dim3(1024), dim3(256), 0, stream>>>(heads + 2 * (size_t)HSZ, Vt);
    k_attn   <<<dim3(512), dim3(128), 0, stream>>>(heads, heads + HSZ, Vt, Ob);
    k_fc     <<<dim3(256), dim3(256), 0, stream>>>(Ob, WT + 3 * 1024 * 1024, q, out);
    k_ln     <<<dim3(4096), dim3(256), 0, stream>>>(out, gamma, beta);
}

// Round 4
// 252.016 us; speedup vs baseline: 1.0263x; 1.0263x over previous
//
#include <hip/hip_runtime.h>
#include <stdint.h>

#define DEV static __device__ __forceinline__

typedef __attribute__((ext_vector_type(4)))  float f32x4;
typedef __attribute__((ext_vector_type(16))) float f32x16;
typedef __bf16 bf16x8 __attribute__((ext_vector_type(8)));

// ---------------- problem constants ----------------
constexpr int Bc = 2, S = 2048, Dm = 1024, H = 16, DH = 64;
constexpr int BS  = Bc * S;                 // 4096 rows
constexpr int HSZ = Bc * H * S * DH;        // 4,194,304 elems per head tensor

// ws layout (byte offsets)
constexpr size_t OFF_QKVB  = 0;              // [3][4096][1024] bf16   25,165,824
constexpr size_t OFF_WT    = 25165824;       // [4][1024][1024] bf16    8,388,608
constexpr size_t OFF_HEADS = 33554432;       // [3][2][16][2048][64]   25,165,824
constexpr size_t OFF_VT    = 58720256;       // [2][16][64][2048]       8,388,608
constexpr size_t OFF_O     = 67108864;       // [4096][1024] bf16       8,388,608

// ---------------- helpers ----------------
DEV uint16_t f2bf(float f) {                  // fp32 -> bf16 RNE (cold paths)
    uint32_t u = __float_as_uint(f);
    uint32_t r = u + 0x7FFFu + ((u >> 16) & 1u);
    return (uint16_t)(r >> 16);
}
DEV uint32_t cvtpk(float lo, float hi) {      // 1-instr packed fp32->bf16x2
    uint32_t r;
    asm("v_cvt_pk_bf16_f32 %0, %1, %2" : "=v"(r) : "v"(lo), "v"(hi));
    return r;
}
DEV float clip15(float x, float c15) {        // clamp(x,0,15) = med3(x,0,15)
    float r;
    asm("v_med3_f32 %0, %1, 0, %2" : "=v"(r) : "v"(x), "v"(c15));
    return r;
}
// XOR swizzle for LDS tiles with 128-byte rows: 16B-chunk ^= (row & 7).
DEV uint32_t swz128(uint32_t byteoff) {
    return byteoff ^ (((byteoff >> 7) & 7u) << 4);
}
DEV void gll16(const void* g, void* l) {      // async global -> LDS, 16B per lane
    auto gp = (const __attribute__((address_space(1))) uint32_t*)g;
    auto lp = (__attribute__((address_space(3))) uint32_t*)l;
    __builtin_amdgcn_global_load_lds(gp, lp, 16, 0, 0);
}
DEV bf16x8 ld_frag(const char* base, uint32_t logical_off) {  // swizzled LDS read
    return __builtin_bit_cast(bf16x8, *(const uint4*)(base + swz128(logical_off)));
}
DEV bf16x8 ld_frag_g(const void* p) {         // 16B global read
    return __builtin_bit_cast(bf16x8, *(const uint4*)p);
}

// ---------------- kernel 1: convert q,k,v fp32 -> bf16 [3][4096][1024] ----------------
__global__ __launch_bounds__(256) void k_convert(const float* __restrict__ q,
                                                 const float* __restrict__ k,
                                                 const float* __restrict__ v,
                                                 uint16_t* __restrict__ out) {
    const int64_t n1 = (int64_t)BS * Dm;
    int64_t i = ((int64_t)blockIdx.x * 256 + threadIdx.x) * 8;
    const float* src; int64_t j;
    if (i < n1)            { src = q; j = i; }
    else if (i < 2 * n1)   { src = k; j = i - n1; }
    else                   { src = v; j = i - 2 * n1; }
    float4 a = *(const float4*)(src + j);
    float4 b = *(const float4*)(src + j + 4);
    union { uint16_t u[8]; uint4 q4; } o;
    o.u[0] = f2bf(a.x); o.u[1] = f2bf(a.y); o.u[2] = f2bf(a.z); o.u[3] = f2bf(a.w);
    o.u[4] = f2bf(b.x); o.u[5] = f2bf(b.y); o.u[6] = f2bf(b.z); o.u[7] = f2bf(b.w);
    *(uint4*)(out + i) = o.q4;
}

// ---------------- kernel 2: W^T bf16 (scale folded into Wq) ----------------
__global__ __launch_bounds__(256) void k_transw(const float* __restrict__ w0,
                                                const float* __restrict__ w1,
                                                const float* __restrict__ w2,
                                                const float* __restrict__ w3,
                                                uint16_t* __restrict__ wt) {
    int mat = blockIdx.y;
    const float* w = (mat == 0) ? w0 : (mat == 1) ? w1 : (mat == 2) ? w2 : w3;
    float scale = (mat == 0) ? 0.125f : 1.0f;     // 1/sqrt(64) folded into Wq
    uint16_t* out = wt + (size_t)mat * 1024 * 1024;
    int tile = blockIdx.x;                        // 16x16 tiles of 64x64
    int tr = (tile >> 4) << 6, tc = (tile & 15) << 6;   // tr = k0, tc = n0
    __shared__ float lds[64][65];
    int t = threadIdx.x;
#pragma unroll
    for (int p = 0; p < 4; ++p) {
        int r = p * 16 + (t >> 4);
        int c = (t & 15) * 4;
        float4 x = *(const float4*)(w + (size_t)(tr + r) * 1024 + tc + c);
        lds[r][c] = x.x; lds[r][c + 1] = x.y; lds[r][c + 2] = x.z; lds[r][c + 3] = x.w;
    }
    __syncthreads();
    int n = t >> 2, kc = (t & 3) * 16;
    union { uint16_t u[16]; uint4 q[2]; } tt;
#pragma unroll
    for (int j = 0; j < 16; ++j) tt.u[j] = f2bf(lds[kc + j][n] * scale);
    uint16_t* dst = out + (size_t)(tc + n) * 1024 + tr + kc;   // WT[n][k]
    *(uint4*)dst = tt.q[0];
    *(uint4*)(dst + 8) = tt.q[1];
}

// ---------------- shared GEMM core: 128x128 tile, BK=64, 4 waves ----------------
struct Acc { f32x4 a[4][4]; };

DEV void stage128(const uint16_t* g, int ldbytes, char* lds) {
    int tid = threadIdx.x;                        // 256 thr x 4 issues x 16B = 16KB
#pragma unroll
    for (int it = 0; it < 4; ++it) {
        uint32_t p = it * 4096 + tid * 16;        // physical LDS offset this lane fills
        uint32_t lo = swz128(p);                  // -> logical: pre-swizzled source
        uint32_t row = lo >> 7, col = lo & 127;
        gll16((const char*)g + (size_t)row * ldbytes + col,
              lds + it * 4096 + (tid & ~63) * 16);  // wave-uniform base + lane*16
    }
}

DEV void gemm_core(const uint16_t* Ta, const uint16_t* Tb, int K,
                   char* la, char* lb, Acc& acc) {
    int lane = threadIdx.x & 63, w = threadIdx.x >> 6;
    int wr = w >> 1, wc = w & 1;
#pragma unroll
    for (int ia = 0; ia < 4; ++ia)
#pragma unroll
        for (int ib = 0; ib < 4; ++ib)
#pragma unroll
            for (int r = 0; r < 4; ++r) acc.a[ia][ib][r] = 0.f;
    for (int k0 = 0; k0 < K; k0 += 64) {
        __syncthreads();                          // prev reads done -> LDS reusable
        stage128(Ta + k0, K * 2, la);
        stage128(Tb + k0, K * 2, lb);
        __syncthreads();                          // staged data visible
#pragma unroll
        for (int kk = 0; kk < 2; ++kk) {
            bf16x8 af[4], bfr[4];
#pragma unroll
            for (int ia = 0; ia < 4; ++ia) {
                uint32_t row = wr * 64 + ia * 16 + (lane & 15);
                af[ia] = ld_frag(la, row * 128 + kk * 64 + (lane >> 4) * 16);
            }
#pragma unroll
            for (int ib = 0; ib < 4; ++ib) {
                uint32_t row = wc * 64 + ib * 16 + (lane & 15);
                bfr[ib] = ld_frag(lb, row * 128 + kk * 64 + (lane >> 4) * 16);
            }
#pragma unroll
            for (int ia = 0; ia < 4; ++ia)
#pragma unroll
                for (int ib = 0; ib < 4; ++ib)
                    acc.a[ia][ib] = __builtin_amdgcn_mfma_f32_16x16x32_bf16(
                        af[ia], bfr[ib], acc.a[ia][ib], 0, 0, 0);
        }
    }
}

// ---------------- kernel 3: fused QKV projection GEMM ----------------
__global__ __launch_bounds__(256) void k_proj(const uint16_t* __restrict__ qkvb,
                                              const uint16_t* __restrict__ WT,
                                              uint16_t* __restrict__ heads) {
    __shared__ char lds[32768];
    int raw = blockIdx.x;                     // 768 blocks; XCD-chunked swizzle
    int blk = (raw & 7) * 96 + (raw >> 3);
    int sel = blk >> 8;
    int t2 = blk & 255; int bm = t2 >> 3, bn = t2 & 7;
    const uint16_t* Act = qkvb + (size_t)sel * BS * Dm + (size_t)bm * 128 * Dm;
    const uint16_t* Wtt = WT   + (size_t)sel * Dm * Dm + (size_t)bn * 128 * Dm;
    Acc acc;
    gemm_core(Wtt, Act, 1024, lds, lds + 16384, acc);   // A=weights, B=acts -> C[n][m]
    uint16_t* out = heads + (size_t)sel * HSZ;
    int lane = threadIdx.x & 63, w = threadIdx.x >> 6;
    int na = bn * 128 + (w >> 1) * 64, mb = bm * 128 + (w & 1) * 64;
#pragma unroll
    for (int ia = 0; ia < 4; ++ia)
#pragma unroll
        for (int ib = 0; ib < 4; ++ib) {
            int n0 = na + ia * 16 + (lane >> 4) * 4;     // 4 consecutive cols
            int m  = mb + ib * 16 + (lane & 15);
            uint2 d;
            d.x = cvtpk(acc.a[ia][ib][0], acc.a[ia][ib][1]);
            d.y = cvtpk(acc.a[ia][ib][2], acc.a[ia][ib][3]);
            int b = m >> 11, s = m & 2047, h = n0 >> 6, dd = n0 & 63;
            *(uint2*)(out + (((size_t)(b * H + h)) * S + s) * 64 + dd) = d;
        }
}

// ---------------- kernel 4: Vh [bh][s][64] -> Vt [bh][64][s] ----------------
__global__ __launch_bounds__(256) void k_transv(const uint16_t* __restrict__ Vh,
                                                uint16_t* __restrict__ Vt) {
    int bh = blockIdx.x >> 5, st = blockIdx.x & 31;
    int s0 = st * 64;
    const uint16_t* src = Vh + (size_t)bh * S * 64 + (size_t)s0 * 64;
    uint16_t* dst = Vt + (size_t)bh * 64 * S;
    __shared__ uint16_t lds[64][65];
    int t = threadIdx.x;
    {
        int r = t >> 2, c = (t & 3) * 16;
        union { uint16_t u[16]; uint4 q[2]; } x;
        x.q[0] = *(const uint4*)(src + (size_t)r * 64 + c);
        x.q[1] = *(const uint4*)(src + (size_t)r * 64 + c + 8);
#pragma unroll
        for (int j = 0; j < 16; ++j) lds[r][c + j] = x.u[j];
    }
    __syncthreads();
    {
        int d = t >> 2, sc = (t & 3) * 16;
        union { uint16_t u[16]; uint4 q[2]; } x;
#pragma unroll
        for (int j = 0; j < 16; ++j) x.u[j] = lds[sc + j][d];
        uint16_t* p = dst + (size_t)d * S + s0 + sc;
        *(uint4*)p = x.q[0];
        *(uint4*)(p + 8) = x.q[1];
    }
}

// ---------------- kernel 5: fused ReLU15 attention ----------------
// 512 blocks = 32 heads x 16 q-blocks of 128 rows; 128 threads = 2 waves,
// each wave owning 64 q-rows (2 subtiles sharing K/V LDS fragments).
// Latency fix (R3 post-mortem): only 1 wave/SIMD is resident, so the per-tile
// __syncthreads vmcnt(0) drain was serially exposed. Now: 3-stage LDS pipeline,
// counted vmcnt(8) (stage t done, t+1 in flight), raw s_barrier (no drain),
// stage t+2 issued right after the barrier. One barrier per tile.
// Safety: reads of buf[(t-1)%3] are consumed (lgkmcnt before MFMA) before each
// wave reaches barrier t; writes into it are issued only after barrier t.
__global__ __launch_bounds__(128) void k_attn(const uint16_t* __restrict__ Qh,
                                              const uint16_t* __restrict__ Kh,
                                              const uint16_t* __restrict__ Vt,
                                              uint16_t* __restrict__ O) {
    __shared__ char kv[3][16384];             // per stage: K [0,8K), V [8K,16K)
    int raw = blockIdx.x;
    int bid = (raw & 7) * 64 + (raw >> 3);    // XCD-chunked: 4 heads per XCD chunk
    int bh = bid >> 4, qb = (bid & 15) * 128;
    int tid = threadIdx.x, lane = tid & 63, w = tid >> 6;
    int l31 = lane & 31, hi = lane >> 5;
    const char* Kbase = (const char*)(Kh + (size_t)bh * S * 64);
    const char* Vbase = (const char*)(Vt + (size_t)bh * 64 * S);

    bf16x8 qf[2][4];                          // Q in regs; 1/TEMP folded into Wq
#pragma unroll
    for (int qs = 0; qs < 2; ++qs) {
        const char* qrow = (const char*)(Qh + (size_t)bh * S * 64
                                         + (size_t)(qb + w * 64 + qs * 32 + l31) * 64);
#pragma unroll
        for (int ks = 0; ks < 4; ++ks)
            qf[qs][ks] = ld_frag_g(qrow + ks * 32 + hi * 16);
    }
    f32x16 oa[2][2];
#pragma unroll
    for (int qs = 0; qs < 2; ++qs)
#pragma unroll
        for (int nt = 0; nt < 2; ++nt)
#pragma unroll
            for (int r = 0; r < 16; ++r) oa[qs][nt][r] = 0.f;
    float c15 = 15.0f;

    auto stageKV = [&](int tile) {            // 8 gll16 per thread per stage
        int bufi = tile % 3;
        int kv0 = tile * 64;
#pragma unroll
        for (int it = 0; it < 4; ++it) {
            uint32_t p = it * 2048 + tid * 16;
            uint32_t lo = swz128(p);
            uint32_t row = lo >> 7, col = lo & 127;
            gll16(Kbase + (size_t)(kv0 + row) * 128 + col,
                  kv[bufi] + it * 2048 + (tid & ~63) * 16);
            gll16(Vbase + (size_t)row * 4096 + (size_t)kv0 * 2 + col,
                  kv[bufi] + 8192 + it * 2048 + (tid & ~63) * 16);
        }
    };

    stageKV(0);
    stageKV(1);
    for (int t = 0; t < 32; ++t) {
        // stage t complete when <=8 outstanding (stage t+1's 8 still in flight)
        if (t < 31) { asm volatile("s_waitcnt vmcnt(8)" ::: "memory"); }
        else        { asm volatile("s_waitcnt vmcnt(0)" ::: "memory"); }
        __builtin_amdgcn_sched_barrier(0);
        __builtin_amdgcn_s_barrier();         // raw barrier: no vmcnt drain
        const char* kb = kv[t % 3];
        const char* vb = kv[t % 3] + 8192;
        if (t < 30) stageKV(t + 2);           // into buf[(t+2)%3] == buf[(t-1)%3]
        __builtin_amdgcn_s_setprio(1);
#pragma unroll
        for (int mt = 0; mt < 2; ++mt) {
            bf16x8 kf[4];
#pragma unroll
            for (int ks = 0; ks < 4; ++ks)
                kf[ks] = ld_frag(kb, (mt * 32 + l31) * 128 + ks * 32 + hi * 16);
            bf16x8 pa[2][2];
#pragma unroll
            for (int qs = 0; qs < 2; ++qs) {
                f32x16 c;
#pragma unroll
                for (int r = 0; r < 16; ++r) c[r] = 0.f;
#pragma unroll
                for (int ks = 0; ks < 4; ++ks)
                    c = __builtin_amdgcn_mfma_f32_32x32x16_bf16(kf[ks], qf[qs][ks], c, 0, 0, 0);
#pragma unroll
                for (int r = 0; r < 16; ++r) c[r] = clip15(c[r], c15);
                // lane holds kv=(r&3)+8*(r>>2)+4*hi; operand needs kv=ks2*16+hi*8+j
#pragma unroll
                for (int ks2 = 0; ks2 < 2; ++ks2) {
                    union { uint32_t w[4]; bf16x8 v; } up;
#pragma unroll
                    for (int jj = 0; jj < 2; ++jj) {
                        uint32_t sA = cvtpk(c[8 * ks2 + 2 * jj],     c[8 * ks2 + 2 * jj + 1]);
                        uint32_t sB = cvtpk(c[8 * ks2 + 4 + 2 * jj], c[8 * ks2 + 4 + 2 * jj + 1]);
                        asm volatile("v_permlane32_swap_b32 %0, %1" : "+v"(sA), "+v"(sB));
                        up.w[jj] = sA; up.w[2 + jj] = sB;
                    }
                    pa[qs][ks2] = up.v;
                }
            }
#pragma unroll
            for (int ks2 = 0; ks2 < 2; ++ks2)
#pragma unroll
                for (int nt = 0; nt < 2; ++nt) {
                    bf16x8 vbf = ld_frag(vb, (nt * 32 + l31) * 128 + mt * 64 + ks2 * 32 + hi * 16);
#pragma unroll
                    for (int qs = 0; qs < 2; ++qs)
                        oa[qs][nt] = __builtin_amdgcn_mfma_f32_32x32x16_bf16(
                            vbf, pa[qs][ks2], oa[qs][nt], 0, 0, 0);
                }
        }
        __builtin_amdgcn_s_setprio(0);
    }
    int b = bh >> 4, h = bh & 15;
#pragma unroll
    for (int qs = 0; qs < 2; ++qs) {
        int q = qb + w * 64 + qs * 32 + l31;                  // C col = q
#pragma unroll
        for (int nt = 0; nt < 2; ++nt)
#pragma unroll
            for (int g = 0; g < 4; ++g) {                      // dv = 8g+4hi+0..3
                uint2 d;
                d.x = cvtpk(oa[qs][nt][4 * g],     oa[qs][nt][4 * g + 1]);
                d.y = cvtpk(oa[qs][nt][4 * g + 2], oa[qs][nt][4 * g + 3]);
                int col = h * 64 + nt * 32 + 8 * g + 4 * hi;
                *(uint2*)(O + ((size_t)(b * S + q)) * 1024 + col) = d;
            }
    }
}

// ---------------- kernel 6: FC GEMM + residual -> d_out fp32 ----------------
__global__ __launch_bounds__(256) void k_fc(const uint16_t* __restrict__ Ob,
                                            const uint16_t* __restrict__ WfcT,
                                            const float* __restrict__ resid,
                                            float* __restrict__ out) {
    __shared__ char lds[32768];
    int raw = blockIdx.x;                     // 256 blocks; XCD swizzle
    int blk = (raw & 7) * 32 + (raw >> 3);
    int bm = blk >> 3, bn = blk & 7;
    const uint16_t* Act = Ob   + (size_t)bm * 128 * Dm;
    const uint16_t* Wtt = WfcT + (size_t)bn * 128 * Dm;
    Acc acc;
    gemm_core(Wtt, Act, 1024, lds, lds + 16384, acc);   // A=weights -> C[n][m]
    int lane = threadIdx.x & 63, w = threadIdx.x >> 6;
    int na = bn * 128 + (w >> 1) * 64, mb = bm * 128 + (w & 1) * 64;
#pragma unroll
    for (int ia = 0; ia < 4; ++ia)
#pragma unroll
        for (int ib = 0; ib < 4; ++ib) {
            int n0 = na + ia * 16 + (lane >> 4) * 4;
            int m  = mb + ib * 16 + (lane & 15);
            size_t idx = (size_t)m * 1024 + n0;
            float4 r4 = *(const float4*)(resid + idx);
            float4 o;
            o.x = acc.a[ia][ib][0] + r4.x;
            o.y = acc.a[ia][ib][1] + r4.y;
            o.z = acc.a[ia][ib][2] + r4.z;
            o.w = acc.a[ia][ib][3] + r4.w;
            *(float4*)(out + idx) = o;
        }
}

// ---------------- kernel 7: LayerNorm in-place on d_out ----------------
__global__ __launch_bounds__(256) void k_ln(float* __restrict__ io,
                                            const float* __restrict__ gamma,
                                            const float* __restrict__ beta) {
    int row = blockIdx.x;
    float* p = io + (size_t)row * 1024;
    int t = threadIdx.x;
    float4 x = *(const float4*)(p + t * 4);
    float s  = x.x + x.y + x.z + x.w;
    float s2 = x.x * x.x + x.y * x.y + x.z * x.z + x.w * x.w;
#pragma unroll
    for (int o = 32; o > 0; o >>= 1) { s += __shfl_xor(s, o); s2 += __shfl_xor(s2, o); }
    __shared__ float red[8];
    int w = t >> 6, lane = t & 63;
    if (lane == 0) { red[w] = s; red[4 + w] = s2; }
    __syncthreads();
    s  = red[0] + red[1] + red[2] + red[3];
    s2 = red[4] + red[5] + red[6] + red[7];
    float mu  = s * (1.f / 1024.f);
    float var = s2 * (1.f / 1024.f) - mu * mu;
    float inv = rsqrtf(var + 1e-6f);
    float4 g  = *(const float4*)(gamma + t * 4);
    float4 bb = *(const float4*)(beta + t * 4);
    x.x = (x.x - mu) * inv * g.x + bb.x;
    x.y = (x.y - mu) * inv * g.y + bb.y;
    x.z = (x.z - mu) * inv * g.z + bb.z;
    x.w = (x.w - mu) * inv * g.w + bb.w;
    *(float4*)(p + t * 4) = x;
}

// ---------------- launcher ----------------
extern "C" void kernel_launch(void* const* d_in, const int* in_sizes, int n_in,
                              void* d_out, int out_size, void* d_ws, size_t ws_size,
                              hipStream_t stream) {
    (void)in_sizes; (void)n_in; (void)out_size; (void)ws_size;
    const float* q     = (const float*)d_in[0];
    const float* k     = (const float*)d_in[1];
    const float* v     = (const float*)d_in[2];
    const float* Wq    = (const float*)d_in[3];
    const float* Wk    = (const float*)d_in[4];
    const float* Wv    = (const float*)d_in[5];
    const float* Wfc   = (const float*)d_in[6];
    const float* gamma = (const float*)d_in[7];
    const float* beta  = (const float*)d_in[8];
    char* ws = (char*)d_ws;
    uint16_t* qkvb  = (uint16_t*)(ws + OFF_QKVB);
    uint16_t* WT    = (uint16_t*)(ws + OFF_WT);
    uint16_t* heads = (uint16_t*)(ws + OFF_HEADS);
    uint16_t* Vt    = (uint16_t*)(ws + OFF_VT);
    uint16_t* Ob    = (uint16_t*)(ws + OFF_O);
    float* out = (float*)d_out;

    k_convert<<<dim3(6144), dim3(256), 0, stream>>>(q, k, v, qkvb);
    k_transw <<<dim3(256, 4), dim3(256), 0, stream>>>(Wq, Wk, Wv, Wfc, WT);
    k_proj   <<<dim3(768), dim3(256), 0, stream>>>(qkvb, WT, heads);
    k_transv <<<dim3(1024), dim3(256), 0, stream>>>(heads + 2 * (size_t)HSZ, Vt);
    k_attn   <<<dim3(512), dim3(128), 0, stream>>>(heads, heads + HSZ, Vt, Ob);
    k_fc     <<<dim3(256), dim3(256), 0, stream>>>(Ob, WT + 3 * 1024 * 1024, q, out);
    k_ln     <<<dim3(4096), dim3(256), 0, stream>>>(out, gamma, beta);
}

// Round 6
// 232.889 us; speedup vs baseline: 1.1106x; 1.0821x over previous
//
#include <hip/hip_runtime.h>
#include <stdint.h>

#define DEV static __device__ __forceinline__

typedef __attribute__((ext_vector_type(4)))  float f32x4;
typedef __attribute__((ext_vector_type(16))) float f32x16;
typedef __bf16 bf16x8 __attribute__((ext_vector_type(8)));

// ---------------- problem constants ----------------
constexpr int Bc = 2, S = 2048, Dm = 1024, H = 16, DH = 64;
constexpr int BS  = Bc * S;                 // 4096 rows
constexpr int HSZ = Bc * H * S * DH;        // 4,194,304 elems per head tensor

// ws layout (byte offsets)
constexpr size_t OFF_QKVB  = 0;              // [3][4096][1024] bf16   25,165,824
constexpr size_t OFF_WT    = 25165824;       // [4][1024][1024] bf16    8,388,608
constexpr size_t OFF_HEADS = 33554432;       // [3][2][16][2048][64]   25,165,824
constexpr size_t OFF_VT    = 58720256;       // [2][16][64][2048]       8,388,608
constexpr size_t OFF_O     = 67108864;       // [4096][1024] bf16       8,388,608
// fc partials [2][4096][1024] fp32 (33,554,432 B) reuse OFF_HEADS..OFF_O
// (heads + Vt are dead after k_attn).

// ---------------- helpers ----------------
DEV uint16_t f2bf(float f) {                  // fp32 -> bf16 RNE (cold paths)
    uint32_t u = __float_as_uint(f);
    uint32_t r = u + 0x7FFFu + ((u >> 16) & 1u);
    return (uint16_t)(r >> 16);
}
DEV uint32_t cvtpk(float lo, float hi) {      // 1-instr packed fp32->bf16x2
    uint32_t r;
    asm("v_cvt_pk_bf16_f32 %0, %1, %2" : "=v"(r) : "v"(lo), "v"(hi));
    return r;
}
DEV float clip15(float x, float c15) {        // clamp(x,0,15) = med3(x,0,15)
    float r;
    asm("v_med3_f32 %0, %1, 0, %2" : "=v"(r) : "v"(x), "v"(c15));
    return r;
}
// XOR swizzle for LDS tiles with 128-byte rows: 16B-chunk ^= (row & 7).
DEV uint32_t swz128(uint32_t byteoff) {
    return byteoff ^ (((byteoff >> 7) & 7u) << 4);
}
DEV void gll16(const void* g, void* l) {      // async global -> LDS, 16B per lane
    auto gp = (const __attribute__((address_space(1))) uint32_t*)g;
    auto lp = (__attribute__((address_space(3))) uint32_t*)l;
    __builtin_amdgcn_global_load_lds(gp, lp, 16, 0, 0);
}
DEV bf16x8 ld_frag(const char* base, uint32_t logical_off) {  // swizzled LDS read
    return __builtin_bit_cast(bf16x8, *(const uint4*)(base + swz128(logical_off)));
}
DEV bf16x8 ld_frag_g(const void* p) {         // 16B global read
    return __builtin_bit_cast(bf16x8, *(const uint4*)p);
}

// ---------------- kernel 1: convert q,k,v fp32 -> bf16 [3][4096][1024] ----------------
__global__ __launch_bounds__(256) void k_convert(const float* __restrict__ q,
                                                 const float* __restrict__ k,
                                                 const float* __restrict__ v,
                                                 uint16_t* __restrict__ out) {
    const int64_t n1 = (int64_t)BS * Dm;
    int64_t i = ((int64_t)blockIdx.x * 256 + threadIdx.x) * 8;
    const float* src; int64_t j;
    if (i < n1)            { src = q; j = i; }
    else if (i < 2 * n1)   { src = k; j = i - n1; }
    else                   { src = v; j = i - 2 * n1; }
    float4 a = *(const float4*)(src + j);
    float4 b = *(const float4*)(src + j + 4);
    union { uint16_t u[8]; uint4 q4; } o;
    o.u[0] = f2bf(a.x); o.u[1] = f2bf(a.y); o.u[2] = f2bf(a.z); o.u[3] = f2bf(a.w);
    o.u[4] = f2bf(b.x); o.u[5] = f2bf(b.y); o.u[6] = f2bf(b.z); o.u[7] = f2bf(b.w);
    *(uint4*)(out + i) = o.q4;
}

// ---------------- kernel 2: W^T bf16 (scale folded into Wq) ----------------
__global__ __launch_bounds__(256) void k_transw(const float* __restrict__ w0,
                                                const float* __restrict__ w1,
                                                const float* __restrict__ w2,
                                                const float* __restrict__ w3,
                                                uint16_t* __restrict__ wt) {
    int mat = blockIdx.y;
    const float* w = (mat == 0) ? w0 : (mat == 1) ? w1 : (mat == 2) ? w2 : w3;
    float scale = (mat == 0) ? 0.125f : 1.0f;     // 1/sqrt(64) folded into Wq
    uint16_t* out = wt + (size_t)mat * 1024 * 1024;
    int tile = blockIdx.x;                        // 16x16 tiles of 64x64
    int tr = (tile >> 4) << 6, tc = (tile & 15) << 6;   // tr = k0, tc = n0
    __shared__ float lds[64][65];
    int t = threadIdx.x;
#pragma unroll
    for (int p = 0; p < 4; ++p) {
        int r = p * 16 + (t >> 4);
        int c = (t & 15) * 4;
        float4 x = *(const float4*)(w + (size_t)(tr + r) * 1024 + tc + c);
        lds[r][c] = x.x; lds[r][c + 1] = x.y; lds[r][c + 2] = x.z; lds[r][c + 3] = x.w;
    }
    __syncthreads();
    int n = t >> 2, kc = (t & 3) * 16;
    union { uint16_t u[16]; uint4 q[2]; } tt;
#pragma unroll
    for (int j = 0; j < 16; ++j) tt.u[j] = f2bf(lds[kc + j][n] * scale);
    uint16_t* dst = out + (size_t)(tc + n) * 1024 + tr + kc;   // WT[n][k]
    *(uint4*)dst = tt.q[0];
    *(uint4*)(dst + 8) = tt.q[1];
}

// ---------------- shared GEMM core: 128x128 tile, BK=64, 4 waves ----------------
struct Acc { f32x4 a[4][4]; };

DEV void stage128(const uint16_t* g, int ldbytes, char* lds) {
    int tid = threadIdx.x;                        // 256 thr x 4 issues x 16B = 16KB
#pragma unroll
    for (int it = 0; it < 4; ++it) {
        uint32_t p = it * 4096 + tid * 16;        // physical LDS offset this lane fills
        uint32_t lo = swz128(p);                  // -> logical: pre-swizzled source
        uint32_t row = lo >> 7, col = lo & 127;
        gll16((const char*)g + (size_t)row * ldbytes + col,
              lds + it * 4096 + (tid & ~63) * 16);  // wave-uniform base + lane*16
    }
}

// ldbytes = row stride of BOTH tiles in bytes (may exceed 2*K for K-split)
DEV void gemm_core(const uint16_t* Ta, const uint16_t* Tb, int K, int ldbytes,
                   char* la, char* lb, Acc& acc) {
    int lane = threadIdx.x & 63, w = threadIdx.x >> 6;
    int wr = w >> 1, wc = w & 1;
#pragma unroll
    for (int ia = 0; ia < 4; ++ia)
#pragma unroll
        for (int ib = 0; ib < 4; ++ib)
#pragma unroll
            for (int r = 0; r < 4; ++r) acc.a[ia][ib][r] = 0.f;
    for (int k0 = 0; k0 < K; k0 += 64) {
        __syncthreads();                          // prev reads done -> LDS reusable
        stage128(Ta + k0, ldbytes, la);
        stage128(Tb + k0, ldbytes, lb);
        __syncthreads();                          // staged data visible
#pragma unroll
        for (int kk = 0; kk < 2; ++kk) {
            bf16x8 af[4], bfr[4];
#pragma unroll
            for (int ia = 0; ia < 4; ++ia) {
                uint32_t row = wr * 64 + ia * 16 + (lane & 15);
                af[ia] = ld_frag(la, row * 128 + kk * 64 + (lane >> 4) * 16);
            }
#pragma unroll
            for (int ib = 0; ib < 4; ++ib) {
                uint32_t row = wc * 64 + ib * 16 + (lane & 15);
                bfr[ib] = ld_frag(lb, row * 128 + kk * 64 + (lane >> 4) * 16);
            }
#pragma unroll
            for (int ia = 0; ia < 4; ++ia)
#pragma unroll
                for (int ib = 0; ib < 4; ++ib)
                    acc.a[ia][ib] = __builtin_amdgcn_mfma_f32_16x16x32_bf16(
                        af[ia], bfr[ib], acc.a[ia][ib], 0, 0, 0);
        }
    }
}

// ---------------- kernel 3: fused QKV projection GEMM ----------------
__global__ __launch_bounds__(256) void k_proj(const uint16_t* __restrict__ qkvb,
                                              const uint16_t* __restrict__ WT,
                                              uint16_t* __restrict__ heads) {
    __shared__ char lds[32768];
    int raw = blockIdx.x;                     // 768 blocks; XCD-chunked swizzle
    int blk = (raw & 7) * 96 + (raw >> 3);
    int sel = blk >> 8;
    int t2 = blk & 255; int bm = t2 >> 3, bn = t2 & 7;
    const uint16_t* Act = qkvb + (size_t)sel * BS * Dm + (size_t)bm * 128 * Dm;
    const uint16_t* Wtt = WT   + (size_t)sel * Dm * Dm + (size_t)bn * 128 * Dm;
    Acc acc;
    gemm_core(Wtt, Act, 1024, 2048, lds, lds + 16384, acc);  // A=weights -> C[n][m]
    uint16_t* out = heads + (size_t)sel * HSZ;
    int lane = threadIdx.x & 63, w = threadIdx.x >> 6;
    int na = bn * 128 + (w >> 1) * 64, mb = bm * 128 + (w & 1) * 64;
#pragma unroll
    for (int ia = 0; ia < 4; ++ia)
#pragma unroll
        for (int ib = 0; ib < 4; ++ib) {
            int n0 = na + ia * 16 + (lane >> 4) * 4;     // 4 consecutive cols
            int m  = mb + ib * 16 + (lane & 15);
            uint2 d;
            d.x = cvtpk(acc.a[ia][ib][0], acc.a[ia][ib][1]);
            d.y = cvtpk(acc.a[ia][ib][2], acc.a[ia][ib][3]);
            int b = m >> 11, s = m & 2047, h = n0 >> 6, dd = n0 & 63;
            *(uint2*)(out + (((size_t)(b * H + h)) * S + s) * 64 + dd) = d;
        }
}

// ---------------- kernel 4: Vh [bh][s][64] -> Vt [bh][64][s] ----------------
__global__ __launch_bounds__(256) void k_transv(const uint16_t* __restrict__ Vh,
                                                uint16_t* __restrict__ Vt) {
    int bh = blockIdx.x >> 5, st = blockIdx.x & 31;
    int s0 = st * 64;
    const uint16_t* src = Vh + (size_t)bh * S * 64 + (size_t)s0 * 64;
    uint16_t* dst = Vt + (size_t)bh * 64 * S;
    __shared__ uint16_t lds[64][65];
    int t = threadIdx.x;
    {
        int r = t >> 2, c = (t & 3) * 16;
        union { uint16_t u[16]; uint4 q[2]; } x;
        x.q[0] = *(const uint4*)(src + (size_t)r * 64 + c);
        x.q[1] = *(const uint4*)(src + (size_t)r * 64 + c + 8);
#pragma unroll
        for (int j = 0; j < 16; ++j) lds[r][c + j] = x.u[j];
    }
    __syncthreads();
    {
        int d = t >> 2, sc = (t & 3) * 16;
        union { uint16_t u[16]; uint4 q[2]; } x;
#pragma unroll
        for (int j = 0; j < 16; ++j) x.u[j] = lds[sc + j][d];
        uint16_t* p = dst + (size_t)d * S + s0 + sc;
        *(uint4*)p = x.q[0];
        *(uint4*)(p + 8) = x.q[1];
    }
}

// ---------------- kernel 5: fused ReLU15 attention ----------------
// 512 blocks = 32 heads x 16 q-blocks of 128 rows; 256 threads = 4 waves:
// wq = w&1 (q-group of 64 rows), wsp = w>>1 (kv-half). Each kv-half runs its
// own 3-stage pipeline over 32 tiles of KVBLK=32 (counted vmcnt(4), raw
// barrier). R4 post-mortem: 1 wave/SIMD left MFMA chains exposed; the split
// doubles resident waves (8/CU = 2/SIMD). Partial O combined via LDS at end.
// Cross-wave visibility: each wave's vmcnt wait precedes the s_barrier, so
// after the barrier the full cooperative stage (both waves' halves) is
// complete and visible. K tile: [32 kv][128B]. V tile packed
// [32 rows][dv r | dv r+32] so rows stay 128B.
__global__ __launch_bounds__(256) void k_attn(const uint16_t* __restrict__ Qh,
                                              const uint16_t* __restrict__ Kh,
                                              const uint16_t* __restrict__ Vt,
                                              uint16_t* __restrict__ O) {
    __shared__ char kvbuf[2][3][8192];        // [split][stage][K 4KB | V 4KB]
    int raw = blockIdx.x;
    int bid = (raw & 7) * 64 + (raw >> 3);    // XCD-chunked: 4 heads per XCD chunk
    int bh = bid >> 4, qb = (bid & 15) * 128;
    int tid = threadIdx.x, lane = tid & 63, w = tid >> 6;
    int wq = w & 1, wsp = w >> 1;             // q-group, kv-split
    int stid = tid & 127;                     // thread id within split
    int l31 = lane & 31, hi = lane >> 5;
    const char* Kbase = (const char*)(Kh + (size_t)bh * S * 64);
    const char* Vbase = (const char*)(Vt + (size_t)bh * 64 * S);

    bf16x8 qf[2][4];                          // Q in regs; 1/TEMP folded into Wq
#pragma unroll
    for (int qs = 0; qs < 2; ++qs) {
        const char* qrow = (const char*)(Qh + (size_t)bh * S * 64
                                         + (size_t)(qb + wq * 64 + qs * 32 + l31) * 64);
#pragma unroll
        for (int ks = 0; ks < 4; ++ks)
            qf[qs][ks] = ld_frag_g(qrow + ks * 32 + hi * 16);
    }
    f32x16 oa[2][2];
#pragma unroll
    for (int qs = 0; qs < 2; ++qs)
#pragma unroll
        for (int nt = 0; nt < 2; ++nt)
#pragma unroll
            for (int r = 0; r < 16; ++r) oa[qs][nt][r] = 0.f;
    float c15 = 15.0f;

    auto stageKV = [&](int tl) {              // 4 gll16 per thread per stage
        int kv0 = wsp * 1024 + tl * 32;       // global kv start for this split
        char* base = (char*)kvbuf + wsp * 24576 + (tl % 3) * 8192;
#pragma unroll
        for (int it = 0; it < 2; ++it) {      // K: [32 kv][128B]
            uint32_t p = it * 2048 + stid * 16;
            uint32_t lo = swz128(p);
            uint32_t row = lo >> 7, col = lo & 127;
            gll16(Kbase + (size_t)(kv0 + row) * 128 + col,
                  base + it * 2048 + (stid & ~63) * 16);
        }
#pragma unroll
        for (int it = 0; it < 2; ++it) {      // V: row r = [dv r | dv r+32], 32 kv each
            uint32_t p = it * 2048 + stid * 16;
            uint32_t lo = swz128(p);
            uint32_t row = lo >> 7, col = lo & 127;
            uint32_t dv = row + (col >> 6) * 32, kvb = col & 63;
            gll16(Vbase + (size_t)dv * 4096 + (size_t)kv0 * 2 + kvb,
                  base + 4096 + it * 2048 + (stid & ~63) * 16);
        }
    };

    stageKV(0);
    stageKV(1);
    for (int t = 0; t < 32; ++t) {
        if (t < 31) { asm volatile("s_waitcnt vmcnt(4)" ::: "memory"); }
        else        { asm volatile("s_waitcnt vmcnt(0)" ::: "memory"); }
        __builtin_amdgcn_sched_barrier(0);
        __builtin_amdgcn_s_barrier();         // raw barrier: stage t visible to split
        const char* kb = (const char*)kvbuf + wsp * 24576 + (t % 3) * 8192;
        const char* vb = kb + 4096;
        if (t < 30) stageKV(t + 2);           // into buf[(t+2)%3] == buf[(t-1)%3]
        __builtin_amdgcn_s_setprio(1);
        bf16x8 kf[4];
#pragma unroll
        for (int ks = 0; ks < 4; ++ks)
            kf[ks] = ld_frag(kb, l31 * 128 + ks * 32 + hi * 16);
        bf16x8 pa[2][2];
#pragma unroll
        for (int qs = 0; qs < 2; ++qs) {
            f32x16 c;
#pragma unroll
            for (int r = 0; r < 16; ++r) c[r] = 0.f;
#pragma unroll
            for (int ks = 0; ks < 4; ++ks)
                c = __builtin_amdgcn_mfma_f32_32x32x16_bf16(kf[ks], qf[qs][ks], c, 0, 0, 0);
#pragma unroll
            for (int r = 0; r < 16; ++r) c[r] = clip15(c[r], c15);
            // lane holds kv=(r&3)+8*(r>>2)+4*hi; B-operand needs kv=ks2*16+hi*8+j
#pragma unroll
            for (int ks2 = 0; ks2 < 2; ++ks2) {
                union { uint32_t w[4]; bf16x8 v; } up;
#pragma unroll
                for (int jj = 0; jj < 2; ++jj) {
                    uint32_t sA = cvtpk(c[8 * ks2 + 2 * jj],     c[8 * ks2 + 2 * jj + 1]);
                    uint32_t sB = cvtpk(c[8 * ks2 + 4 + 2 * jj], c[8 * ks2 + 4 + 2 * jj + 1]);
                    asm volatile("v_permlane32_swap_b32 %0, %1" : "+v"(sA), "+v"(sB));
                    up.w[jj] = sA; up.w[2 + jj] = sB;
                }
                pa[qs][ks2] = up.v;
            }
        }
#pragma unroll
        for (int ks2 = 0; ks2 < 2; ++ks2)
#pragma unroll
            for (int nt = 0; nt < 2; ++nt) {
                bf16x8 vf = ld_frag(vb, l31 * 128 + nt * 64 + ks2 * 32 + hi * 16);
#pragma unroll
                for (int qs = 0; qs < 2; ++qs)
                    oa[qs][nt] = __builtin_amdgcn_mfma_f32_32x32x16_bf16(
                        vf, pa[qs][ks2], oa[qs][nt], 0, 0, 0);
            }
        __builtin_amdgcn_s_setprio(0);
    }
    // ---- combine the two kv-halves via LDS (stride 68 floats, 16B-aligned;
    //      ~8-way bank aliasing but runs once -- negligible) ----
    __syncthreads();
    float* xch = (float*)kvbuf;
    float* xp = xch + (size_t)(wq * 64 + lane) * 68;
    if (wsp == 1) {
#pragma unroll
        for (int qs = 0; qs < 2; ++qs)
#pragma unroll
            for (int nt = 0; nt < 2; ++nt) {
                union { f32x16 v; float4 q4[4]; } u; u.v = oa[qs][nt];
#pragma unroll
                for (int r4 = 0; r4 < 4; ++r4)
                    *(float4*)(xp + qs * 32 + nt * 16 + r4 * 4) = u.q4[r4];
            }
    }
    __syncthreads();
    if (wsp == 0) {
        int b = bh >> 4, h = bh & 15;
#pragma unroll
        for (int qs = 0; qs < 2; ++qs) {
            int q = qb + wq * 64 + qs * 32 + l31;              // C col = q
#pragma unroll
            for (int nt = 0; nt < 2; ++nt) {
#pragma unroll
                for (int r = 0; r < 16; ++r)
                    oa[qs][nt][r] += xp[qs * 32 + nt * 16 + r];
#pragma unroll
                for (int g = 0; g < 4; ++g) {                  // dv = 8g+4hi+0..3
                    uint2 d;
                    d.x = cvtpk(oa[qs][nt][4 * g],     oa[qs][nt][4 * g + 1]);
                    d.y = cvtpk(oa[qs][nt][4 * g + 2], oa[qs][nt][4 * g + 3]);
                    int col = h * 64 + nt * 32 + 8 * g + 4 * hi;
                    *(uint2*)(O + ((size_t)(b * S + q)) * 1024 + col) = d;
                }
            }
        }
    }
}

// ---------------- kernel 6: FC GEMM, K-split x2 -> fp32 partials ----------------
__global__ __launch_bounds__(256) void k_fc(const uint16_t* __restrict__ Ob,
                                            const uint16_t* __restrict__ WfcT,
                                            float* __restrict__ part) {
    __shared__ char lds[32768];
    int raw = blockIdx.x;                     // 512 blocks; XCD swizzle
    int blk = (raw & 7) * 64 + (raw >> 3);
    int ks = blk >> 8;                        // K-split half
    int t2 = blk & 255; int bm = t2 >> 3, bn = t2 & 7;
    const uint16_t* Act = Ob   + (size_t)bm * 128 * Dm + ks * 512;
    const uint16_t* Wtt = WfcT + (size_t)bn * 128 * Dm + ks * 512;
    Acc acc;
    gemm_core(Wtt, Act, 512, 2048, lds, lds + 16384, acc);   // A=weights -> C[n][m]
    float* o = part + (size_t)ks * BS * Dm;
    int lane = threadIdx.x & 63, w = threadIdx.x >> 6;
    int na = bn * 128 + (w >> 1) * 64, mb = bm * 128 + (w & 1) * 64;
#pragma unroll
    for (int ia = 0; ia < 4; ++ia)
#pragma unroll
        for (int ib = 0; ib < 4; ++ib) {
            int n0 = na + ia * 16 + (lane >> 4) * 4;
            int m  = mb + ib * 16 + (lane & 15);
            size_t idx = (size_t)m * 1024 + n0;
            float4 v;
            v.x = acc.a[ia][ib][0]; v.y = acc.a[ia][ib][1];
            v.z = acc.a[ia][ib][2]; v.w = acc.a[ia][ib][3];
            *(float4*)(o + idx) = v;
        }
}

// ---------------- kernel 7: fused (p0+p1+residual) + LayerNorm -> d_out ----------------
__global__ __launch_bounds__(256) void k_ln(const float* __restrict__ p0,
                                            const float* __restrict__ p1,
                                            const float* __restrict__ resid,
                                            const float* __restrict__ gamma,
                                            const float* __restrict__ beta,
                                            float* __restrict__ out) {
    int row = blockIdx.x;
    size_t off = (size_t)row * 1024 + threadIdx.x * 4;
    int t = threadIdx.x;
    float4 a = *(const float4*)(p0 + off);
    float4 b2 = *(const float4*)(p1 + off);
    float4 r = *(const float4*)(resid + off);
    float4 x;
    x.x = a.x + b2.x + r.x; x.y = a.y + b2.y + r.y;
    x.z = a.z + b2.z + r.z; x.w = a.w + b2.w + r.w;
    float s  = x.x + x.y + x.z + x.w;
    float s2 = x.x * x.x + x.y * x.y + x.z * x.z + x.w * x.w;
#pragma unroll
    for (int o = 32; o > 0; o >>= 1) { s += __shfl_xor(s, o); s2 += __shfl_xor(s2, o); }
    __shared__ float red[8];
    int w = t >> 6, lane = t & 63;
    if (lane == 0) { red[w] = s; red[4 + w] = s2; }
    __syncthreads();
    s  = red[0] + red[1] + red[2] + red[3];
    s2 = red[4] + red[5] + red[6] + red[7];
    float mu  = s * (1.f / 1024.f);
    float var = s2 * (1.f / 1024.f) - mu * mu;
    float inv = rsqrtf(var + 1e-6f);
    float4 g  = *(const float4*)(gamma + t * 4);
    float4 bb = *(const float4*)(beta + t * 4);
    x.x = (x.x - mu) * inv * g.x + bb.x;
    x.y = (x.y - mu) * inv * g.y + bb.y;
    x.z = (x.z - mu) * inv * g.z + bb.z;
    x.w = (x.w - mu) * inv * g.w + bb.w;
    *(float4*)(out + off) = x;
}

// ---------------- launcher ----------------
extern "C" void kernel_launch(void* const* d_in, const int* in_sizes, int n_in,
                              void* d_out, int out_size, void* d_ws, size_t ws_size,
                              hipStream_t stream) {
    (void)in_sizes; (void)n_in; (void)out_size; (void)ws_size;
    const float* q     = (const float*)d_in[0];
    const float* k     = (const float*)d_in[1];
    const float* v     = (const float*)d_in[2];
    const float* Wq    = (const float*)d_in[3];
    const float* Wk    = (const float*)d_in[4];
    const float* Wv    = (const float*)d_in[5];
    const float* Wfc   = (const float*)d_in[6];
    const float* gamma = (const float*)d_in[7];
    const float* beta  = (const float*)d_in[8];
    char* ws = (char*)d_ws;
    uint16_t* qkvb  = (uint16_t*)(ws + OFF_QKVB);
    uint16_t* WT    = (uint16_t*)(ws + OFF_WT);
    uint16_t* heads = (uint16_t*)(ws + OFF_HEADS);
    uint16_t* Vt    = (uint16_t*)(ws + OFF_VT);
    uint16_t* Ob    = (uint16_t*)(ws + OFF_O);
    float* fcpart   = (float*)(ws + OFF_HEADS);   // reuses heads+Vt after k_attn
    float* out = (float*)d_out;

    k_convert<<<dim3(6144), dim3(256), 0, stream>>>(q, k, v, qkvb);
    k_transw <<<dim3(256, 4), dim3(256), 0, stream>>>(Wq, Wk, Wv, Wfc, WT);
    k_proj   <<<dim3(768), dim3(256), 0, stream>>>(qkvb, WT, heads);
    k_transv <<<dim3(1024), dim3(256), 0, stream>>>(heads + 2 * (size_t)HSZ, Vt);
    k_attn   <<<dim3(512), dim3(256), 0, stream>>>(heads, heads + HSZ, Vt, Ob);
    k_fc     <<<dim3(512), dim3(256), 0, stream>>>(Ob, WT + 3 * 1024 * 1024, fcpart);
    k_ln     <<<dim3(4096), dim3(256), 0, stream>>>(fcpart, fcpart + (size_t)BS * Dm,
                                                    q, gamma, beta, out);
}